// Round 12
// baseline (595.258 us; speedup 1.0000x reference)
//
#include <hip/hip_runtime.h>

typedef unsigned int uint;
typedef unsigned short ushort;
typedef __attribute__((ext_vector_type(8))) short short8v;  // 8 bf16 bit patterns
typedef __attribute__((ext_vector_type(4))) float f32x4;

#define IN_DIM 256
#define HID 128
#define BN_EPS 1e-5f
#define NSHARD 8

__device__ __forceinline__ float bf2f(ushort u) { return __uint_as_float(((uint)u) << 16); }
__device__ __forceinline__ ushort f2bf(float f) {
    uint u = __float_as_uint(f);
    return (ushort)((u + 0x7fffu + ((u >> 16) & 1u)) >> 16);  // RNE
}
__device__ __forceinline__ uint cvt_pk_bf16(float a, float b) {
    uint r;
    asm("v_cvt_pk_bf16_f32 %0, %1, %2" : "=v"(r) : "v"(a), "v"(b));
    return r;
}
// async global->LDS, 16B/lane. LDS dest = wave-uniform base + lane*16;
// global src is PER-LANE (pre-swizzled-source pattern).
__device__ __forceinline__ void gload_lds16(const void* g, void* l) {
    __builtin_amdgcn_global_load_lds(
        (const __attribute__((address_space(1))) uint*)g,
        (__attribute__((address_space(3))) uint*)l, 16, 0, 0);
}

// ---------------- CSR build ----------------

// nt load: streaming ei read bypasses L2 allocation (keeps L2 for deg lines).
__global__ void count_deg_kernel(const int* __restrict__ ei, int* __restrict__ deg, int E) {
    int e = blockIdx.x * blockDim.x + threadIdx.x;
    if (e < E) atomicAdd(&deg[__builtin_nontemporal_load(ei + E + e)], 1);
}

#define SCAN_THREADS 256
#define SCAN_ELEMS 1024

__global__ __launch_bounds__(SCAN_THREADS) void scan1_kernel(const int* __restrict__ deg,
                                                             int* __restrict__ outp,
                                                             int* __restrict__ bsum, int n) {
    __shared__ int sdata[SCAN_THREADS];
    int t = threadIdx.x;
    int base = blockIdx.x * SCAN_ELEMS + t * 4;
    int v0 = 0, v1 = 0, v2 = 0, v3 = 0;
    if (base + 0 < n) v0 = deg[base + 0];
    if (base + 1 < n) v1 = deg[base + 1];
    if (base + 2 < n) v2 = deg[base + 2];
    if (base + 3 < n) v3 = deg[base + 3];
    int s = v0 + v1 + v2 + v3;
    sdata[t] = s;
    __syncthreads();
    int val = s;
    for (int off = 1; off < SCAN_THREADS; off <<= 1) {
        int add = (t >= off) ? sdata[t - off] : 0;
        __syncthreads();
        val += add;
        sdata[t] = val;
        __syncthreads();
    }
    int excl = val - s;
    if (base + 0 < n) outp[base + 0] = excl;
    if (base + 1 < n) outp[base + 1] = excl + v0;
    if (base + 2 < n) outp[base + 2] = excl + v0 + v1;
    if (base + 3 < n) outp[base + 3] = excl + v0 + v1 + v2;
    if (t == SCAN_THREADS - 1) bsum[blockIdx.x] = val;
}

__global__ void scan2_kernel(int* bsum, int nb) {
    if (threadIdx.x == 0 && blockIdx.x == 0) {
        int acc = 0;
        for (int i = 0; i < nb; i++) { int v = bsum[i]; bsum[i] = acc; acc += v; }
        bsum[nb] = acc;
    }
}

__global__ void scan3_kernel(int* __restrict__ row_ptr, const int* __restrict__ bsum, int n, int nb) {
    int i = blockIdx.x * blockDim.x + threadIdx.x;
    if (i < n) row_ptr[i] += bsum[i >> 10];
    else if (i == n) row_ptr[n] = bsum[nb];
}

// XCD-sharded CSR fill (round-5 WIN). round-12: nt loads on the ei streams
// so the 12.8MB/pass read doesn't evict the esrc dirty lines from the XCD L2
// (round-11 counters: WRITE_SIZE 71MB = partial-line evictions caused by the
// read stream thrashing the slice).
__global__ __launch_bounds__(256) void fill_csr_sharded(const int* __restrict__ ei,
                                                        int* __restrict__ cursor,
                                                        int* __restrict__ esrc,
                                                        int E, int shardSize) {
    int s = blockIdx.x & (NSHARD - 1);
    int rank = blockIdx.x >> 3;
    int nteam = gridDim.x >> 3;
    int lo = s * shardSize;
    int hi = lo + shardSize;
    int stride = nteam * blockDim.x;
    for (int e = rank * blockDim.x + threadIdx.x; e < E; e += stride) {
        int d = __builtin_nontemporal_load(ei + E + e);
        if (d >= lo && d < hi) {
            int src = __builtin_nontemporal_load(ei + e);
            int pos = atomicAdd(&cursor[d], 1);
            esrc[pos] = src;
        }
    }
}

// ---------------- Weight pre-pack: fp32 [k][c] -> bf16 [c][k] (frag-ready) ----------------

__global__ __launch_bounds__(256) void pack_win(const float* __restrict__ W, ushort* __restrict__ Wt) {
    int idx = blockIdx.x * 256 + threadIdx.x;
    int k = idx >> 7, c = idx & 127;
    Wt[c * IN_DIM + k] = f2bf(W[idx]);
}

__global__ __launch_bounds__(256) void pack_wcat(const float* __restrict__ Wl,
                                                 const float* __restrict__ Wr,
                                                 ushort* __restrict__ Wt) {
    int idx = blockIdx.x * 256 + threadIdx.x;
    int layer = idx >> 15;
    int rem = idx & 32767;
    int k = rem >> 7, c = rem & 127;
    float v = (k < HID) ? Wl[layer * HID * HID + k * HID + c]
                        : Wr[layer * HID * HID + (k - HID) * HID + c];
    Wt[layer * (HID * 256) + c * 256 + k] = f2bf(v);
}

// ---------------- Aggregation: mean over in-neighbors (bf16 rows) ----------------
// round 12: 2 nodes/wave, 32 lanes x uint2 (4 cols/lane) -> 512B per wave
// load instruction (2 rows), 2x edges in flight. Per-column edge-sum order
// identical to before (bit-for-bit). nt on esrc stream (no reuse within a
// dispatch; keeps L2 for h rows).

__global__ __launch_bounds__(256) void sage_mean_bf16(const ushort* __restrict__ h,
                                                      const int* __restrict__ row_ptr,
                                                      const int* __restrict__ esrc,
                                                      ushort* __restrict__ meanb, int n) {
    int node = blockIdx.x * 8 + (threadIdx.x >> 5);
    if (node >= n) return;
    int lane = threadIdx.x & 31;
    const ushort* hc = h + lane * 4;
    int start = row_ptr[node];
    int end = row_ptr[node + 1];
    float a0 = 0.f, a1 = 0.f, a2 = 0.f, a3 = 0.f;
    int j = start;
    for (; j + 7 < end; j += 8) {
        uint2 v[8];
        #pragma unroll
        for (int q = 0; q < 8; q++) {
            int s = __builtin_nontemporal_load(esrc + j + q);
            v[q] = *(const uint2*)(hc + (size_t)s * HID);
        }
        #pragma unroll
        for (int q = 0; q < 8; q++) {
            a0 += bf2f((ushort)(v[q].x & 0xffffu));
            a1 += bf2f((ushort)(v[q].x >> 16));
            a2 += bf2f((ushort)(v[q].y & 0xffffu));
            a3 += bf2f((ushort)(v[q].y >> 16));
        }
    }
    for (; j < end; ++j) {
        int s = __builtin_nontemporal_load(esrc + j);
        uint2 v = *(const uint2*)(hc + (size_t)s * HID);
        a0 += bf2f((ushort)(v.x & 0xffffu));
        a1 += bf2f((ushort)(v.x >> 16));
        a2 += bf2f((ushort)(v.y & 0xffffu));
        a3 += bf2f((ushort)(v.y >> 16));
    }
    int deg = end - start;
    float inv = 1.0f / (float)(deg > 1 ? deg : 1);
    uint2 o;
    o.x = (uint)f2bf(a0 * inv) | (((uint)f2bf(a1 * inv)) << 16);
    o.y = (uint)f2bf(a2 * inv) | (((uint)f2bf(a3 * inv)) << 16);
    *(uint2*)(meanb + (size_t)node * HID + lane * 4) = o;
}

// ---------------- Input GEMM: h = relu(x @ W_in + b_in), MFMA ----------------
// A-tile (32x256 fp32 = 32KB) staged once/block via global_load_lds with
// XOR-swizzled source; shared by 4 waves. B in regs from packed Wt.

__global__ __launch_bounds__(256) void input_gemm_mfma(const float* __restrict__ x,
                                                       const ushort* __restrict__ Wt,
                                                       const float* __restrict__ b,
                                                       ushort* __restrict__ hout, int n) {
    __shared__ float Axs[32 * IN_DIM];  // 32KB
    int t = threadIdx.x;
    int l = t & 63;
    int wv = t >> 6;
    int colbase = wv * 32;
    int lr = l & 15;
    int grp = l >> 4;
    int ko = grp * 8;

    short8v Bf[8][2];
    #pragma unroll
    for (int ks = 0; ks < 8; ks++) {
        #pragma unroll
        for (int nt = 0; nt < 2; nt++) {
            int c = colbase + nt * 16 + lr;
            Bf[ks][nt] = *(const short8v*)(Wt + (size_t)c * IN_DIM + ks * 32 + ko);
        }
    }
    float bias0 = b[colbase + lr];
    float bias1 = b[colbase + 16 + lr];

    int ntiles = (n + 31) >> 5;
    for (int tile = blockIdx.x; tile < ntiles; tile += gridDim.x) {
        int row0 = tile * 32;
        __syncthreads();
        {
            const char* xb = (const char*)(x + (size_t)row0 * IN_DIM);
            char* lb = (char*)Axs;
            #pragma unroll
            for (int i = 0; i < 8; i++) {
                int off = i * 4096 + t * 16;
                int src = off ^ (((off >> 10) & 7) << 4);
                gload_lds16(xb + src, lb + i * 4096 + wv * 1024);
            }
        }
        __syncthreads();
        f32x4 acc00 = {0.f,0.f,0.f,0.f}, acc01 = {0.f,0.f,0.f,0.f};
        f32x4 acc10 = {0.f,0.f,0.f,0.f}, acc11 = {0.f,0.f,0.f,0.f};
        #pragma unroll
        for (int m = 0; m < 2; m++) {
            int r = m * 16 + lr;
            int rswz = (r & 7) << 4;
            const char* rowp = (const char*)Axs + r * 1024;
            short8v Af[8];
            #pragma unroll
            for (int ks = 0; ks < 8; ks++) {
                int kb = (ko + ks * 32) * 4;
                float4 p = *(const float4*)(rowp + (kb ^ rswz));
                float4 q = *(const float4*)(rowp + ((kb + 16) ^ rswz));
                union { uint4 u; short8v s; } cv;
                cv.u.x = cvt_pk_bf16(p.x, p.y);
                cv.u.y = cvt_pk_bf16(p.z, p.w);
                cv.u.z = cvt_pk_bf16(q.x, q.y);
                cv.u.w = cvt_pk_bf16(q.z, q.w);
                Af[ks] = cv.s;
            }
            if (m == 0) {
                #pragma unroll
                for (int ks = 0; ks < 8; ks++) {
                    acc00 = __builtin_amdgcn_mfma_f32_16x16x32_bf16(Af[ks], Bf[ks][0], acc00, 0, 0, 0);
                    acc01 = __builtin_amdgcn_mfma_f32_16x16x32_bf16(Af[ks], Bf[ks][1], acc01, 0, 0, 0);
                }
            } else {
                #pragma unroll
                for (int ks = 0; ks < 8; ks++) {
                    acc10 = __builtin_amdgcn_mfma_f32_16x16x32_bf16(Af[ks], Bf[ks][0], acc10, 0, 0, 0);
                    acc11 = __builtin_amdgcn_mfma_f32_16x16x32_bf16(Af[ks], Bf[ks][1], acc11, 0, 0, 0);
                }
            }
        }
        #pragma unroll
        for (int m = 0; m < 2; m++) {
            int rbase = row0 + m * 16 + grp * 4;
            f32x4 a0 = m == 0 ? acc00 : acc10;
            f32x4 a1 = m == 0 ? acc01 : acc11;
            #pragma unroll
            for (int r = 0; r < 4; r++) {
                int rowd = rbase + r;
                if (rowd < n) {
                    float z0 = a0[r] + bias0; z0 = z0 > 0.f ? z0 : 0.f;
                    float z1 = a1[r] + bias1; z1 = z1 > 0.f ? z1 : 0.f;
                    hout[(size_t)rowd * HID + colbase + lr] = f2bf(z0);
                    hout[(size_t)rowd * HID + colbase + 16 + lr] = f2bf(z1);
                }
            }
        }
    }
}

// ---------------- Fused SAGE layer, MFMA ----------------
// 64-row tile; Ams/Ahs staged via global_load_lds + XOR swizzle, shared by
// 4 waves. Residual read from Ahs. B in regs from packed WcatT.

__global__ __launch_bounds__(256) void sage_layer_mfma(const ushort* __restrict__ h,
                                                       const ushort* __restrict__ mh,
                                                       ushort* __restrict__ hout,
                                                       const ushort* __restrict__ Wt,
                                                       const float* __restrict__ bl,
                                                       const float* __restrict__ br,
                                                       const float* __restrict__ gamma,
                                                       const float* __restrict__ beta,
                                                       const float* __restrict__ bmean,
                                                       const float* __restrict__ bvar,
                                                       int n) {
    __shared__ ushort Ams[64 * HID];  // 16KB
    __shared__ ushort Ahs[64 * HID];  // 16KB
    int t = threadIdx.x;
    int l = t & 63;
    int wv = t >> 6;
    int colbase = wv * 32;
    int lr = l & 15;
    int grp = l >> 4;
    int ko = grp * 8;

    short8v Bf[8][2];
    #pragma unroll
    for (int ks = 0; ks < 8; ks++) {
        #pragma unroll
        for (int nt = 0; nt < 2; nt++) {
            int c = colbase + nt * 16 + lr;
            Bf[ks][nt] = *(const short8v*)(Wt + (size_t)c * 256 + ks * 32 + ko);
        }
    }
    int c0 = colbase + lr;
    int c1 = c0 + 16;
    float scale0 = gamma[c0] * rsqrtf(bvar[c0] + BN_EPS);
    float scale1 = gamma[c1] * rsqrtf(bvar[c1] + BN_EPS);
    float shift0 = beta[c0] + (bl[c0] + br[c0] - bmean[c0]) * scale0;
    float shift1 = beta[c1] + (bl[c1] + br[c1] - bmean[c1]) * scale1;

    int ntiles = (n + 63) >> 6;
    for (int tile = blockIdx.x; tile < ntiles; tile += gridDim.x) {
        int row0 = tile * 64;
        __syncthreads();
        {
            const char* mb = (const char*)(mh + (size_t)row0 * HID);
            const char* hb = (const char*)(h + (size_t)row0 * HID);
            char* lm = (char*)Ams;
            char* lh = (char*)Ahs;
            #pragma unroll
            for (int i = 0; i < 4; i++) {
                int off = i * 4096 + t * 16;
                int src = off ^ (((off >> 8) & 7) << 4);
                gload_lds16(mb + src, lm + i * 4096 + wv * 1024);
                gload_lds16(hb + src, lh + i * 4096 + wv * 1024);
            }
        }
        __syncthreads();
        #pragma unroll
        for (int m = 0; m < 4; m++) {
            int r = m * 16 + lr;
            int rswz = (r & 7) << 4;
            const char* mrow = (const char*)Ams + r * 256;
            const char* hrow = (const char*)Ahs + r * 256;
            short8v Af[8];
            #pragma unroll
            for (int ks = 0; ks < 4; ks++) {
                int kb = (ko + ks * 32) * 2;
                Af[ks] = *(const short8v*)(mrow + (kb ^ rswz));
            }
            #pragma unroll
            for (int ks = 4; ks < 8; ks++) {
                int kb = (ko + (ks - 4) * 32) * 2;
                Af[ks] = *(const short8v*)(hrow + (kb ^ rswz));
            }
            f32x4 acc0 = {0.f,0.f,0.f,0.f};
            f32x4 acc1 = {0.f,0.f,0.f,0.f};
            #pragma unroll
            for (int ks = 0; ks < 8; ks++) {
                acc0 = __builtin_amdgcn_mfma_f32_16x16x32_bf16(Af[ks], Bf[ks][0], acc0, 0, 0, 0);
                acc1 = __builtin_amdgcn_mfma_f32_16x16x32_bf16(Af[ks], Bf[ks][1], acc1, 0, 0, 0);
            }
            int rbase = m * 16 + grp * 4;
            #pragma unroll
            for (int r2 = 0; r2 < 4; r2++) {
                int rloc = rbase + r2;
                int rowd = row0 + rloc;
                if (rowd < n) {
                    int rs = (rloc & 7) << 4;
                    float res0 = bf2f(*(const ushort*)((const char*)Ahs + rloc * 256 + ((c0 * 2) ^ rs)));
                    float res1 = bf2f(*(const ushort*)((const char*)Ahs + rloc * 256 + ((c1 * 2) ^ rs)));
                    float z0 = acc0[r2] * scale0 + shift0; z0 = z0 > 0.f ? z0 : 0.f;
                    float z1 = acc1[r2] * scale1 + shift1; z1 = z1 > 0.f ? z1 : 0.f;
                    hout[(size_t)rowd * HID + c0] = f2bf(z0 + res0);
                    hout[(size_t)rowd * HID + c1] = f2bf(z1 + res1);
                }
            }
        }
    }
}

// ---------------- Classifier + log_softmax (bf16 h) ----------------

__global__ __launch_bounds__(256) void classifier_bf16(const ushort* __restrict__ h,
                                                       const float* __restrict__ Wc,
                                                       const float* __restrict__ bc,
                                                       float* __restrict__ outp, int n) {
    __shared__ float Wcs[HID * 2];
    int t = threadIdx.x;
    if (t < 64) *(float4*)&Wcs[t * 4] = *(const float4*)&Wc[t * 4];
    __syncthreads();
    int rowInBlk = t >> 4;
    int sub = t & 15;
    int row = blockIdx.x * 16 + rowInBlk;
    float l0 = 0.f, l1 = 0.f;
    if (row < n) {
        const ushort* hr = h + (size_t)row * HID + sub * 8;
        uint4 v = *(const uint4*)hr;
        float e0 = bf2f((ushort)(v.x & 0xffffu)), e1 = bf2f((ushort)(v.x >> 16));
        float e2 = bf2f((ushort)(v.y & 0xffffu)), e3 = bf2f((ushort)(v.y >> 16));
        float e4 = bf2f((ushort)(v.z & 0xffffu)), e5 = bf2f((ushort)(v.z >> 16));
        float e6 = bf2f((ushort)(v.w & 0xffffu)), e7 = bf2f((ushort)(v.w >> 16));
        int k0 = sub * 8;
        l0 += e0 * Wcs[(k0 + 0) * 2] + e1 * Wcs[(k0 + 1) * 2] + e2 * Wcs[(k0 + 2) * 2] + e3 * Wcs[(k0 + 3) * 2];
        l0 += e4 * Wcs[(k0 + 4) * 2] + e5 * Wcs[(k0 + 5) * 2] + e6 * Wcs[(k0 + 6) * 2] + e7 * Wcs[(k0 + 7) * 2];
        l1 += e0 * Wcs[(k0 + 0) * 2 + 1] + e1 * Wcs[(k0 + 1) * 2 + 1] + e2 * Wcs[(k0 + 2) * 2 + 1] + e3 * Wcs[(k0 + 3) * 2 + 1];
        l1 += e4 * Wcs[(k0 + 4) * 2 + 1] + e5 * Wcs[(k0 + 5) * 2 + 1] + e6 * Wcs[(k0 + 6) * 2 + 1] + e7 * Wcs[(k0 + 7) * 2 + 1];
    }
    #pragma unroll
    for (int off = 1; off < 16; off <<= 1) {
        l0 += __shfl_xor(l0, off);
        l1 += __shfl_xor(l1, off);
    }
    if (sub == 0 && row < n) {
        l0 += bc[0];
        l1 += bc[1];
        float m = fmaxf(l0, l1);
        float lse = m + logf(expf(l0 - m) + expf(l1 - m));
        outp[(size_t)row * 2 + 0] = l0 - lse;
        outp[(size_t)row * 2 + 1] = l1 - lse;
    }
}

// ---------------- host ----------------

extern "C" void kernel_launch(void* const* d_in, const int* in_sizes, int n_in,
                              void* d_out, int out_size, void* d_ws, size_t ws_size,
                              hipStream_t stream) {
    const float* x     = (const float*)d_in[0];
    const int*   ei    = (const int*)d_in[1];
    const float* W_in  = (const float*)d_in[2];
    const float* b_in  = (const float*)d_in[3];
    const float* W_l   = (const float*)d_in[4];
    const float* b_l   = (const float*)d_in[5];
    const float* W_r   = (const float*)d_in[6];
    const float* b_r   = (const float*)d_in[7];
    const float* bn_g  = (const float*)d_in[8];
    const float* bn_b  = (const float*)d_in[9];
    const float* bn_m  = (const float*)d_in[10];
    const float* bn_v  = (const float*)d_in[11];
    const float* W_cls = (const float*)d_in[12];
    const float* b_cls = (const float*)d_in[13];
    float* outp = (float*)d_out;

    const int N = in_sizes[0] / IN_DIM;   // 100000
    const int E = in_sizes[1] / 2;        // 1600000

    char* w = (char*)d_ws;
    const size_t HB = (size_t)N * HID * sizeof(ushort);          // 25.6 MB per buffer
    ushort* hA     = (ushort*)(w);
    ushort* hB     = (ushort*)(w + HB);
    ushort* meanb  = (ushort*)(w + 2 * HB);
    ushort* Wt_in  = (ushort*)(w + 3 * HB);                      // 64 KB
    ushort* WcatT  = (ushort*)(w + 3 * HB + 65536);              // 256 KB
    char*  ints    = w + 3 * HB + 65536 + 262144;
    int*   row_ptr = (int*)(ints);                               // N+1 ints
    int*   cursor  = (int*)(ints + 400128);
    int*   bsum    = (int*)(ints + 800256);
    int*   esrc    = (int*)(ints + 801280);                      // E ints

    const int nbScan = (N + SCAN_ELEMS - 1) / SCAN_ELEMS;
    const int shardSize = (N + NSHARD - 1) / NSHARD;             // 12500

    // --- weight pre-pack (bf16, frag-ready [c][k]) ---
    pack_win<<<128, 256, 0, stream>>>(W_in, Wt_in);
    pack_wcat<<<512, 256, 0, stream>>>(W_l, W_r, WcatT);

    // --- CSR build ---
    hipMemsetAsync(cursor, 0, (size_t)N * sizeof(int), stream);
    count_deg_kernel<<<(E + 255) / 256, 256, 0, stream>>>(ei, cursor, E);
    scan1_kernel<<<nbScan, SCAN_THREADS, 0, stream>>>(cursor, row_ptr, bsum, N);
    scan2_kernel<<<1, 64, 0, stream>>>(bsum, nbScan);
    scan3_kernel<<<(N + 256) / 256, 256, 0, stream>>>(row_ptr, bsum, N, nbScan);
    hipMemcpyAsync(cursor, row_ptr, (size_t)N * sizeof(int), hipMemcpyDeviceToDevice, stream);
    fill_csr_sharded<<<2048, 256, 0, stream>>>(ei, cursor, esrc, E, shardSize);

    // --- input projection (fp32 x -> bf16 h) ---
    input_gemm_mfma<<<(N + 31) / 32, 256, 0, stream>>>(x, Wt_in, b_in, hA, N);

    // --- 4 SAGE layers ---
    ushort* hcur = hA;
    ushort* hoth = hB;
    for (int i = 0; i < 4; i++) {
        sage_mean_bf16<<<(N + 7) / 8, 256, 0, stream>>>(hcur, row_ptr, esrc, meanb, N);
        sage_layer_mfma<<<(N + 63) / 64, 256, 0, stream>>>(hcur, meanb, hoth,
                                                  WcatT + (size_t)i * HID * 256,
                                                  b_l + i * HID, b_r + i * HID,
                                                  bn_g + i * HID, bn_b + i * HID,
                                                  bn_m + i * HID, bn_v + i * HID, N);
        ushort* tmp = hcur; hcur = hoth; hoth = tmp;
    }

    // --- classifier + log_softmax ---
    classifier_bf16<<<(N + 15) / 16, 256, 0, stream>>>(hcur, W_cls, b_cls, outp, N);
}

// Round 13
// 529.442 us; speedup vs baseline: 1.1243x; 1.1243x over previous
//
#include <hip/hip_runtime.h>

typedef unsigned int uint;
typedef unsigned short ushort;
typedef __attribute__((ext_vector_type(8))) short short8v;  // 8 bf16 bit patterns
typedef __attribute__((ext_vector_type(4))) float f32x4;

#define IN_DIM 256
#define HID 128
#define BN_EPS 1e-5f

__device__ __forceinline__ float bf2f(ushort u) { return __uint_as_float(((uint)u) << 16); }
__device__ __forceinline__ ushort f2bf(float f) {
    uint u = __float_as_uint(f);
    return (ushort)((u + 0x7fffu + ((u >> 16) & 1u)) >> 16);  // RNE
}
__device__ __forceinline__ uint cvt_pk_bf16(float a, float b) {
    uint r;
    asm("v_cvt_pk_bf16_f32 %0, %1, %2" : "=v"(r) : "v"(a), "v"(b));
    return r;
}
__device__ __forceinline__ void gload_lds16(const void* g, void* l) {
    __builtin_amdgcn_global_load_lds(
        (const __attribute__((address_space(1))) uint*)g,
        (__attribute__((address_space(3))) uint*)l, 16, 0, 0);
}

// ================= CSR build: radix partition (round 13) =================
// Replaces count_deg + scan1/2/3 + memcpy + fill_csr (110us of scatter
// amplification) with sequential / block-private-range writes only.
// Buckets of 512 nodes; nbuck = ceil(N/512) = 196 <= 256.

// Pass A1: per-chunk bucket histogram (LDS counters, sequential writes out).
__global__ __launch_bounds__(256) void hist_kernel(const int* __restrict__ ei,
                                                   int* __restrict__ histG,
                                                   int E, int chunk) {
    __shared__ int hcnt[256];
    int t = threadIdx.x;
    hcnt[t] = 0;
    __syncthreads();
    int e0 = blockIdx.x * chunk;
    int e1 = min(E, e0 + chunk);
    for (int e = e0 + t; e < e1; e += 256)
        atomicAdd(&hcnt[__builtin_nontemporal_load(ei + E + e) >> 9], 1);
    __syncthreads();
    histG[blockIdx.x * 256 + t] = hcnt[t];
}

// Pass A2: bucket starts + per-(chunk,bucket) write bases.
__global__ __launch_bounds__(256) void basescan_kernel(const int* __restrict__ histG,
                                                       int* __restrict__ baseG,
                                                       int* __restrict__ bucketStart,
                                                       int nchunk, int nbuck, int E) {
    __shared__ int sA[256], sB[256];
    int t = threadIdx.x;
    int tot = 0;
    for (int c = 0; c < nchunk; c++) tot += histG[c * 256 + t];
    sA[t] = tot;
    __syncthreads();
    int* src = sA; int* dst = sB;
    for (int off = 1; off < 256; off <<= 1) {
        int v = src[t];
        if (t >= off) v += src[t - off];
        dst[t] = v;
        __syncthreads();
        int* tmp = src; src = dst; dst = tmp;
    }
    int excl = src[t] - tot;
    if (t < nbuck) bucketStart[t] = excl;
    if (t == 0) bucketStart[nbuck] = E;
    int running = excl;
    for (int c = 0; c < nchunk; c++) {
        baseG[c * 256 + t] = running;
        running += histG[c * 256 + t];
    }
}

// Pass A3: scatter (src,dst) pairs into bucket regions. Each chunk-block owns
// a CONTIGUOUS, fully-covered sub-range of every bucket region -> near-full-
// line write efficiency regardless of XCD mapping.
__global__ __launch_bounds__(256) void partition_kernel(const int* __restrict__ ei,
                                                        const int* __restrict__ baseG,
                                                        uint2* __restrict__ ebuck,
                                                        int E, int chunk) {
    __shared__ int cur[256];
    int t = threadIdx.x;
    cur[t] = baseG[blockIdx.x * 256 + t];
    __syncthreads();
    int e0 = blockIdx.x * chunk;
    int e1 = min(E, e0 + chunk);
    for (int e = e0 + t; e < e1; e += 256) {
        int d = __builtin_nontemporal_load(ei + E + e);
        int s = __builtin_nontemporal_load(ei + e);
        int pos = atomicAdd(&cur[d >> 9], 1);
        ebuck[pos] = make_uint2((uint)s, (uint)d);
    }
}

// Pass B: one block per bucket. Degrees in LDS -> LDS scan -> writes its
// row_ptr slice (replaces count_deg + scans) -> scatter src into a 64KB LDS
// image (LDS atomics) -> stream out coalesced. Overflow (cnt>16384, ~90
// sigma) falls back to direct global scatter.
__global__ __launch_bounds__(256) void bucket_build(const uint2* __restrict__ ebuck,
                                                    const int* __restrict__ bucketStart,
                                                    int* __restrict__ row_ptr,
                                                    int* __restrict__ esrc,
                                                    int n, int nbuck) {
    __shared__ int deg[512];
    __shared__ int sA[512], sB[512];
    __shared__ int cur[512];
    __shared__ int img[16384];
    int b = blockIdx.x;
    int t = threadIdx.x;
    int lo = b << 9;
    int hi = min(n, lo + 512);
    int nn = hi - lo;
    int eStart = bucketStart[b];
    int eEnd = bucketStart[b + 1];
    int cnt = eEnd - eStart;
    for (int i = t; i < 512; i += 256) deg[i] = 0;
    __syncthreads();
    for (int e = eStart + t; e < eEnd; e += 256) {
        uint2 p = ebuck[e];
        atomicAdd(&deg[(int)p.y - lo], 1);
    }
    __syncthreads();
    for (int i = t; i < 512; i += 256) sA[i] = deg[i];
    __syncthreads();
    int* src = sA; int* dst = sB;
    for (int off = 1; off < 512; off <<= 1) {
        for (int i = t; i < 512; i += 256) {
            int v = src[i];
            if (i >= off) v += src[i - off];
            dst[i] = v;
        }
        __syncthreads();
        int* tmp = src; src = dst; dst = tmp;
    }
    // src = inclusive scan of deg; exclusive = src[i]-deg[i]
    for (int i = t; i < 512; i += 256) cur[i] = src[i] - deg[i];
    __syncthreads();
    for (int i = t; i < nn; i += 256) row_ptr[lo + i] = eStart + cur[i];
    if (b == nbuck - 1 && t == 0) row_ptr[n] = eEnd;
    __syncthreads();  // row_ptr reads of cur must precede phase-3 bumps
    if (cnt <= 16384) {
        for (int e = eStart + t; e < eEnd; e += 256) {
            uint2 p = ebuck[e];
            int pos = atomicAdd(&cur[(int)p.y - lo], 1);
            img[pos] = (int)p.x;
        }
        __syncthreads();
        for (int i = t; i < cnt; i += 256) esrc[eStart + i] = img[i];
    } else {
        for (int e = eStart + t; e < eEnd; e += 256) {
            uint2 p = ebuck[e];
            int pos = atomicAdd(&cur[(int)p.y - lo], 1);
            esrc[eStart + pos] = (int)p.x;
        }
    }
}

// ---------------- Weight pre-pack: fp32 [k][c] -> bf16 [c][k] ----------------

__global__ __launch_bounds__(256) void pack_win(const float* __restrict__ W, ushort* __restrict__ Wt) {
    int idx = blockIdx.x * 256 + threadIdx.x;
    int k = idx >> 7, c = idx & 127;
    Wt[c * IN_DIM + k] = f2bf(W[idx]);
}

__global__ __launch_bounds__(256) void pack_wcat(const float* __restrict__ Wl,
                                                 const float* __restrict__ Wr,
                                                 ushort* __restrict__ Wt) {
    int idx = blockIdx.x * 256 + threadIdx.x;
    int layer = idx >> 15;
    int rem = idx & 32767;
    int k = rem >> 7, c = rem & 127;
    float v = (k < HID) ? Wl[layer * HID * HID + k * HID + c]
                        : Wr[layer * HID * HID + (k - HID) * HID + c];
    Wt[layer * (HID * 256) + c * 256 + k] = f2bf(v);
}

// ---------------- Aggregation (round-11 winner, restored) ----------------
// one wave per node, lane owns 2 cols (uint), 16 edges in flight.

__global__ __launch_bounds__(256) void sage_mean_bf16(const ushort* __restrict__ h,
                                                      const int* __restrict__ row_ptr,
                                                      const int* __restrict__ esrc,
                                                      ushort* __restrict__ meanb, int n) {
    int node = blockIdx.x * 4 + (threadIdx.x >> 6);
    if (node >= n) return;
    int lane = threadIdx.x & 63;
    int start = row_ptr[node];
    int end = row_ptr[node + 1];
    float ax = 0.f, ay = 0.f;
    int j = start;
    for (; j + 15 < end; j += 16) {
        uint v[16];
        #pragma unroll
        for (int q = 0; q < 16; q++)
            v[q] = *(const uint*)(h + (size_t)esrc[j + q] * HID + lane * 2);
        #pragma unroll
        for (int q = 0; q < 16; q++) {
            ax += bf2f((ushort)(v[q] & 0xffffu));
            ay += bf2f((ushort)(v[q] >> 16));
        }
    }
    for (; j + 7 < end; j += 8) {
        uint v[8];
        #pragma unroll
        for (int q = 0; q < 8; q++)
            v[q] = *(const uint*)(h + (size_t)esrc[j + q] * HID + lane * 2);
        #pragma unroll
        for (int q = 0; q < 8; q++) {
            ax += bf2f((ushort)(v[q] & 0xffffu));
            ay += bf2f((ushort)(v[q] >> 16));
        }
    }
    for (; j < end; ++j) {
        uint v0 = *(const uint*)(h + (size_t)esrc[j] * HID + lane * 2);
        ax += bf2f((ushort)(v0 & 0xffffu));
        ay += bf2f((ushort)(v0 >> 16));
    }
    int deg = end - start;
    float inv = 1.0f / (float)(deg > 1 ? deg : 1);
    uint o = (uint)f2bf(ax * inv) | (((uint)f2bf(ay * inv)) << 16);
    *(uint*)(meanb + (size_t)node * HID + lane * 2) = o;
}

// ---------------- Input GEMM (round-11 winner) ----------------

__global__ __launch_bounds__(256) void input_gemm_mfma(const float* __restrict__ x,
                                                       const ushort* __restrict__ Wt,
                                                       const float* __restrict__ b,
                                                       ushort* __restrict__ hout, int n) {
    __shared__ float Axs[32 * IN_DIM];  // 32KB
    int t = threadIdx.x;
    int l = t & 63;
    int wv = t >> 6;
    int colbase = wv * 32;
    int lr = l & 15;
    int grp = l >> 4;
    int ko = grp * 8;

    short8v Bf[8][2];
    #pragma unroll
    for (int ks = 0; ks < 8; ks++) {
        #pragma unroll
        for (int nt = 0; nt < 2; nt++) {
            int c = colbase + nt * 16 + lr;
            Bf[ks][nt] = *(const short8v*)(Wt + (size_t)c * IN_DIM + ks * 32 + ko);
        }
    }
    float bias0 = b[colbase + lr];
    float bias1 = b[colbase + 16 + lr];

    int ntiles = (n + 31) >> 5;
    for (int tile = blockIdx.x; tile < ntiles; tile += gridDim.x) {
        int row0 = tile * 32;
        __syncthreads();
        {
            const char* xb = (const char*)(x + (size_t)row0 * IN_DIM);
            char* lb = (char*)Axs;
            #pragma unroll
            for (int i = 0; i < 8; i++) {
                int off = i * 4096 + t * 16;
                int src = off ^ (((off >> 10) & 7) << 4);
                gload_lds16(xb + src, lb + i * 4096 + wv * 1024);
            }
        }
        __syncthreads();
        f32x4 acc00 = {0.f,0.f,0.f,0.f}, acc01 = {0.f,0.f,0.f,0.f};
        f32x4 acc10 = {0.f,0.f,0.f,0.f}, acc11 = {0.f,0.f,0.f,0.f};
        #pragma unroll
        for (int m = 0; m < 2; m++) {
            int r = m * 16 + lr;
            int rswz = (r & 7) << 4;
            const char* rowp = (const char*)Axs + r * 1024;
            short8v Af[8];
            #pragma unroll
            for (int ks = 0; ks < 8; ks++) {
                int kb = (ko + ks * 32) * 4;
                float4 p = *(const float4*)(rowp + (kb ^ rswz));
                float4 q = *(const float4*)(rowp + ((kb + 16) ^ rswz));
                union { uint4 u; short8v s; } cv;
                cv.u.x = cvt_pk_bf16(p.x, p.y);
                cv.u.y = cvt_pk_bf16(p.z, p.w);
                cv.u.z = cvt_pk_bf16(q.x, q.y);
                cv.u.w = cvt_pk_bf16(q.z, q.w);
                Af[ks] = cv.s;
            }
            if (m == 0) {
                #pragma unroll
                for (int ks = 0; ks < 8; ks++) {
                    acc00 = __builtin_amdgcn_mfma_f32_16x16x32_bf16(Af[ks], Bf[ks][0], acc00, 0, 0, 0);
                    acc01 = __builtin_amdgcn_mfma_f32_16x16x32_bf16(Af[ks], Bf[ks][1], acc01, 0, 0, 0);
                }
            } else {
                #pragma unroll
                for (int ks = 0; ks < 8; ks++) {
                    acc10 = __builtin_amdgcn_mfma_f32_16x16x32_bf16(Af[ks], Bf[ks][0], acc10, 0, 0, 0);
                    acc11 = __builtin_amdgcn_mfma_f32_16x16x32_bf16(Af[ks], Bf[ks][1], acc11, 0, 0, 0);
                }
            }
        }
        #pragma unroll
        for (int m = 0; m < 2; m++) {
            int rbase = row0 + m * 16 + grp * 4;
            f32x4 a0 = m == 0 ? acc00 : acc10;
            f32x4 a1 = m == 0 ? acc01 : acc11;
            #pragma unroll
            for (int r = 0; r < 4; r++) {
                int rowd = rbase + r;
                if (rowd < n) {
                    float z0 = a0[r] + bias0; z0 = z0 > 0.f ? z0 : 0.f;
                    float z1 = a1[r] + bias1; z1 = z1 > 0.f ? z1 : 0.f;
                    hout[(size_t)rowd * HID + colbase + lr] = f2bf(z0);
                    hout[(size_t)rowd * HID + colbase + 16 + lr] = f2bf(z1);
                }
            }
        }
    }
}

// ---------------- Fused SAGE layer (round-11 winner) ----------------

__global__ __launch_bounds__(256) void sage_layer_mfma(const ushort* __restrict__ h,
                                                       const ushort* __restrict__ mh,
                                                       ushort* __restrict__ hout,
                                                       const ushort* __restrict__ Wt,
                                                       const float* __restrict__ bl,
                                                       const float* __restrict__ br,
                                                       const float* __restrict__ gamma,
                                                       const float* __restrict__ beta,
                                                       const float* __restrict__ bmean,
                                                       const float* __restrict__ bvar,
                                                       int n) {
    __shared__ ushort Ams[64 * HID];  // 16KB
    __shared__ ushort Ahs[64 * HID];  // 16KB
    int t = threadIdx.x;
    int l = t & 63;
    int wv = t >> 6;
    int colbase = wv * 32;
    int lr = l & 15;
    int grp = l >> 4;
    int ko = grp * 8;

    short8v Bf[8][2];
    #pragma unroll
    for (int ks = 0; ks < 8; ks++) {
        #pragma unroll
        for (int nt = 0; nt < 2; nt++) {
            int c = colbase + nt * 16 + lr;
            Bf[ks][nt] = *(const short8v*)(Wt + (size_t)c * 256 + ks * 32 + ko);
        }
    }
    int c0 = colbase + lr;
    int c1 = c0 + 16;
    float scale0 = gamma[c0] * rsqrtf(bvar[c0] + BN_EPS);
    float scale1 = gamma[c1] * rsqrtf(bvar[c1] + BN_EPS);
    float shift0 = beta[c0] + (bl[c0] + br[c0] - bmean[c0]) * scale0;
    float shift1 = beta[c1] + (bl[c1] + br[c1] - bmean[c1]) * scale1;

    int ntiles = (n + 63) >> 6;
    for (int tile = blockIdx.x; tile < ntiles; tile += gridDim.x) {
        int row0 = tile * 64;
        __syncthreads();
        {
            const char* mb = (const char*)(mh + (size_t)row0 * HID);
            const char* hb = (const char*)(h + (size_t)row0 * HID);
            char* lm = (char*)Ams;
            char* lh = (char*)Ahs;
            #pragma unroll
            for (int i = 0; i < 4; i++) {
                int off = i * 4096 + t * 16;
                int src = off ^ (((off >> 8) & 7) << 4);
                gload_lds16(mb + src, lm + i * 4096 + wv * 1024);
                gload_lds16(hb + src, lh + i * 4096 + wv * 1024);
            }
        }
        __syncthreads();
        #pragma unroll
        for (int m = 0; m < 4; m++) {
            int r = m * 16 + lr;
            int rswz = (r & 7) << 4;
            const char* mrow = (const char*)Ams + r * 256;
            const char* hrow = (const char*)Ahs + r * 256;
            short8v Af[8];
            #pragma unroll
            for (int ks = 0; ks < 4; ks++) {
                int kb = (ko + ks * 32) * 2;
                Af[ks] = *(const short8v*)(mrow + (kb ^ rswz));
            }
            #pragma unroll
            for (int ks = 4; ks < 8; ks++) {
                int kb = (ko + (ks - 4) * 32) * 2;
                Af[ks] = *(const short8v*)(hrow + (kb ^ rswz));
            }
            f32x4 acc0 = {0.f,0.f,0.f,0.f};
            f32x4 acc1 = {0.f,0.f,0.f,0.f};
            #pragma unroll
            for (int ks = 0; ks < 8; ks++) {
                acc0 = __builtin_amdgcn_mfma_f32_16x16x32_bf16(Af[ks], Bf[ks][0], acc0, 0, 0, 0);
                acc1 = __builtin_amdgcn_mfma_f32_16x16x32_bf16(Af[ks], Bf[ks][1], acc1, 0, 0, 0);
            }
            int rbase = m * 16 + grp * 4;
            #pragma unroll
            for (int r2 = 0; r2 < 4; r2++) {
                int rloc = rbase + r2;
                int rowd = row0 + rloc;
                if (rowd < n) {
                    int rs = (rloc & 7) << 4;
                    float res0 = bf2f(*(const ushort*)((const char*)Ahs + rloc * 256 + ((c0 * 2) ^ rs)));
                    float res1 = bf2f(*(const ushort*)((const char*)Ahs + rloc * 256 + ((c1 * 2) ^ rs)));
                    float z0 = acc0[r2] * scale0 + shift0; z0 = z0 > 0.f ? z0 : 0.f;
                    float z1 = acc1[r2] * scale1 + shift1; z1 = z1 > 0.f ? z1 : 0.f;
                    hout[(size_t)rowd * HID + c0] = f2bf(z0 + res0);
                    hout[(size_t)rowd * HID + c1] = f2bf(z1 + res1);
                }
            }
        }
    }
}

// ---------------- Classifier + log_softmax ----------------

__global__ __launch_bounds__(256) void classifier_bf16(const ushort* __restrict__ h,
                                                       const float* __restrict__ Wc,
                                                       const float* __restrict__ bc,
                                                       float* __restrict__ outp, int n) {
    __shared__ float Wcs[HID * 2];
    int t = threadIdx.x;
    if (t < 64) *(float4*)&Wcs[t * 4] = *(const float4*)&Wc[t * 4];
    __syncthreads();
    int rowInBlk = t >> 4;
    int sub = t & 15;
    int row = blockIdx.x * 16 + rowInBlk;
    float l0 = 0.f, l1 = 0.f;
    if (row < n) {
        const ushort* hr = h + (size_t)row * HID + sub * 8;
        uint4 v = *(const uint4*)hr;
        float e0 = bf2f((ushort)(v.x & 0xffffu)), e1 = bf2f((ushort)(v.x >> 16));
        float e2 = bf2f((ushort)(v.y & 0xffffu)), e3 = bf2f((ushort)(v.y >> 16));
        float e4 = bf2f((ushort)(v.z & 0xffffu)), e5 = bf2f((ushort)(v.z >> 16));
        float e6 = bf2f((ushort)(v.w & 0xffffu)), e7 = bf2f((ushort)(v.w >> 16));
        int k0 = sub * 8;
        l0 += e0 * Wcs[(k0 + 0) * 2] + e1 * Wcs[(k0 + 1) * 2] + e2 * Wcs[(k0 + 2) * 2] + e3 * Wcs[(k0 + 3) * 2];
        l0 += e4 * Wcs[(k0 + 4) * 2] + e5 * Wcs[(k0 + 5) * 2] + e6 * Wcs[(k0 + 6) * 2] + e7 * Wcs[(k0 + 7) * 2];
        l1 += e0 * Wcs[(k0 + 0) * 2 + 1] + e1 * Wcs[(k0 + 1) * 2 + 1] + e2 * Wcs[(k0 + 2) * 2 + 1] + e3 * Wcs[(k0 + 3) * 2 + 1];
        l1 += e4 * Wcs[(k0 + 4) * 2 + 1] + e5 * Wcs[(k0 + 5) * 2 + 1] + e6 * Wcs[(k0 + 6) * 2 + 1] + e7 * Wcs[(k0 + 7) * 2 + 1];
    }
    #pragma unroll
    for (int off = 1; off < 16; off <<= 1) {
        l0 += __shfl_xor(l0, off);
        l1 += __shfl_xor(l1, off);
    }
    if (sub == 0 && row < n) {
        l0 += bc[0];
        l1 += bc[1];
        float m = fmaxf(l0, l1);
        float lse = m + logf(expf(l0 - m) + expf(l1 - m));
        outp[(size_t)row * 2 + 0] = l0 - lse;
        outp[(size_t)row * 2 + 1] = l1 - lse;
    }
}

// ---------------- host ----------------

extern "C" void kernel_launch(void* const* d_in, const int* in_sizes, int n_in,
                              void* d_out, int out_size, void* d_ws, size_t ws_size,
                              hipStream_t stream) {
    const float* x     = (const float*)d_in[0];
    const int*   ei    = (const int*)d_in[1];
    const float* W_in  = (const float*)d_in[2];
    const float* b_in  = (const float*)d_in[3];
    const float* W_l   = (const float*)d_in[4];
    const float* b_l   = (const float*)d_in[5];
    const float* W_r   = (const float*)d_in[6];
    const float* b_r   = (const float*)d_in[7];
    const float* bn_g  = (const float*)d_in[8];
    const float* bn_b  = (const float*)d_in[9];
    const float* bn_m  = (const float*)d_in[10];
    const float* bn_v  = (const float*)d_in[11];
    const float* W_cls = (const float*)d_in[12];
    const float* b_cls = (const float*)d_in[13];
    float* outp = (float*)d_out;

    const int N = in_sizes[0] / IN_DIM;   // 100000
    const int E = in_sizes[1] / 2;        // 1600000

    char* w = (char*)d_ws;
    const size_t HB = (size_t)N * HID * sizeof(ushort);          // 25.6 MB per buffer
    ushort* hA     = (ushort*)(w);
    ushort* hB     = (ushort*)(w + HB);
    ushort* meanb  = (ushort*)(w + 2 * HB);
    ushort* Wt_in  = (ushort*)(w + 3 * HB);                      // 64 KB
    ushort* WcatT  = (ushort*)(w + 3 * HB + 65536);              // 256 KB
    size_t off = 3 * HB + 65536 + 262144;
    int* row_ptr = (int*)(w + off);  off += ((size_t)(N + 1) * 4 + 255) & ~(size_t)255;
    int* esrc    = (int*)(w + off);  off += (size_t)E * 4;
    uint2* ebuck = (uint2*)(w + off); off += (size_t)E * 8;
    int* histG   = (int*)(w + off);  off += 256 * 256 * 4;
    int* baseG   = (int*)(w + off);  off += 256 * 256 * 4;
    int* bucketStart = (int*)(w + off); off += 4096;

    const int nbuck = (N + 511) >> 9;                            // 196
    const int nchunk = 256;
    const int chunk = (E + nchunk - 1) / nchunk;                 // 6250

    // --- weight pre-pack ---
    pack_win<<<128, 256, 0, stream>>>(W_in, Wt_in);
    pack_wcat<<<512, 256, 0, stream>>>(W_l, W_r, WcatT);

    // --- CSR build (radix partition; also produces row_ptr) ---
    hist_kernel<<<nchunk, 256, 0, stream>>>(ei, histG, E, chunk);
    basescan_kernel<<<1, 256, 0, stream>>>(histG, baseG, bucketStart, nchunk, nbuck, E);
    partition_kernel<<<nchunk, 256, 0, stream>>>(ei, baseG, ebuck, E, chunk);
    bucket_build<<<nbuck, 256, 0, stream>>>(ebuck, bucketStart, row_ptr, esrc, N, nbuck);

    // --- input projection ---
    input_gemm_mfma<<<(N + 31) / 32, 256, 0, stream>>>(x, Wt_in, b_in, hA, N);

    // --- 4 SAGE layers ---
    ushort* hcur = hA;
    ushort* hoth = hB;
    for (int i = 0; i < 4; i++) {
        sage_mean_bf16<<<(N + 3) / 4, 256, 0, stream>>>(hcur, row_ptr, esrc, meanb, N);
        sage_layer_mfma<<<(N + 63) / 64, 256, 0, stream>>>(hcur, meanb, hoth,
                                                  WcatT + (size_t)i * HID * 256,
                                                  b_l + i * HID, b_r + i * HID,
                                                  bn_g + i * HID, bn_b + i * HID,
                                                  bn_m + i * HID, bn_v + i * HID, N);
        ushort* tmp = hcur; hcur = hoth; hoth = tmp;
    }

    // --- classifier + log_softmax ---
    classifier_bf16<<<(N + 15) / 16, 256, 0, stream>>>(hcur, W_cls, b_cls, outp, N);
}